// Round 11
// baseline (1663.764 us; speedup 1.0000x reference)
//
#include <hip/hip_runtime.h>

#define B_ 8
#define L_ 512
#define D_ 64
#define H_ 256
#define GH 1024   // 4*H
#define EPS_ 1e-5f
#define POISON_ 0xAAAAAAAAu  // harness poisons d_ws to 0xAA bytes every launch

typedef float f32x4 __attribute__((ext_vector_type(4)));
typedef _Float16 half8 __attribute__((ext_vector_type(8)));
typedef unsigned int u32x4 __attribute__((ext_vector_type(4)));

__device__ __forceinline__ unsigned short f2h(float f) {
  _Float16 h = (_Float16)f;
  return __builtin_bit_cast(unsigned short, h);
}
__device__ __forceinline__ float h2f(unsigned short s) {
  _Float16 h = __builtin_bit_cast(_Float16, s);
  return (float)h;
}
__device__ __forceinline__ float fast_tanh(float x) {
  return 1.0f - 2.0f / (1.0f + __expf(2.0f * x));
}
__device__ __forceinline__ float fast_sig(float x) {
  return 1.0f / (1.0f + __expf(-x));
}
__device__ __forceinline__ bool ok4(u32x4 v) {
  return v.x != POISON_ && v.y != POISON_ && v.z != POISON_ && v.w != POISON_;
}
// One device-coherent (sc1) 16B poll load; single waitcnt.
__device__ __forceinline__ void poll1(const unsigned short* p, u32x4& v) {
  asm volatile("global_load_dwordx4 %0, %1, off sc1\n\ts_waitcnt vmcnt(0)"
               : "=&v"(v) : "v"(p) : "memory");
}
// Two batched 16B poll loads; one waitcnt covers both (latencies overlap).
__device__ __forceinline__ void poll2(const unsigned short* p0, const unsigned short* p1,
                                      u32x4& v0, u32x4& v1) {
  asm volatile(
      "global_load_dwordx4 %0, %2, off sc1\n\t"
      "global_load_dwordx4 %1, %3, off sc1\n\t"
      "s_waitcnt vmcnt(0)"
      : "=&v"(v0), "=&v"(v1) : "v"(p0), "v"(p1) : "memory");
}

// ---------------- K1: causal score rows (plain dot + additive) ----------------
__global__ void scores_kernel(const float* __restrict__ src,
                              float* __restrict__ Sp, float* __restrict__ Sa) {
  const int l = blockIdx.x, b = blockIdx.y;
  __shared__ float xl[D_];
  if (threadIdx.x < D_) xl[threadIdx.x] = src[(b * L_ + l) * D_ + threadIdx.x];
  __syncthreads();
  for (int m = threadIdx.x; m <= l; m += blockDim.x) {
    const float4* xr = (const float4*)&src[(b * L_ + m) * D_];
    float dp = 0.f, da = 0.f;
#pragma unroll
    for (int d4 = 0; d4 < D_ / 4; ++d4) {
      float4 v = xr[d4];
      dp += xl[d4*4+0]*v.x + xl[d4*4+1]*v.y + xl[d4*4+2]*v.z + xl[d4*4+3]*v.w;
      da += fast_tanh(xl[d4*4+0]+v.x) + fast_tanh(xl[d4*4+1]+v.y)
          + fast_tanh(xl[d4*4+2]+v.z) + fast_tanh(xl[d4*4+3]+v.w);
    }
    Sp[(b * L_ + l) * L_ + m] = dp;
    Sa[(b * L_ + l) * L_ + m] = da;
  }
}

// ---------------- K2: causal softmax + P@x ----------------
__global__ void softmax_av_kernel(const float* __restrict__ src, const float* __restrict__ Sp,
                                  const float* __restrict__ Sa, float* __restrict__ outk) {
  const int l = blockIdx.x, b = blockIdx.y, k = blockIdx.z;
  const int lane = threadIdx.x;  // 64 threads = 1 wave
  __shared__ float p[L_];
  const float* row = (k == 1) ? &Sa[(b * L_ + l) * L_] : &Sp[(b * L_ + l) * L_];
  const float scale = (k == 2) ? 0.125f : 1.0f;
  float mx = -1e30f;
  for (int m = lane; m <= l; m += 64) { float v = row[m] * scale; p[m] = v; mx = fmaxf(mx, v); }
#pragma unroll
  for (int off = 32; off > 0; off >>= 1) mx = fmaxf(mx, __shfl_xor(mx, off, 64));
  float sum = 0.f;
  for (int m = lane; m <= l; m += 64) { float e = __expf(p[m] - mx); p[m] = e; sum += e; }
#pragma unroll
  for (int off = 32; off > 0; off >>= 1) sum += __shfl_xor(sum, off, 64);
  __syncthreads();
  const float inv = 1.0f / sum;
  float acc = 0.f;
  for (int m = 0; m <= l; ++m) acc += p[m] * src[(b * L_ + m) * D_ + lane];
  outk[((k * B_ + b) * L_ + l) * D_ + lane] = acc * inv;
}

// ---------------- K3a: weighted combine ----------------
__global__ void combine_kernel(const float* __restrict__ outk, const float* __restrict__ attn_w,
                               float* __restrict__ attn) {
  int i = blockIdx.x * blockDim.x + threadIdx.x;
  if (i >= B_ * L_ * D_) return;
  int ld = i & (L_ * D_ - 1);
  float w0 = attn_w[ld], w1 = attn_w[L_ * D_ + ld], w2 = attn_w[2 * L_ * D_ + ld];
  float o0 = outk[i], o1 = outk[B_ * L_ * D_ + i], o2 = outk[2 * B_ * L_ * D_ + i];
  attn[i] = (o0 * w0 + o1 * w1 + o2 * w2) / (w0 + w1 + w2);
}

// ---------------- K3b: BatchNorm over (B,L) per feature, 3 lines ----------------
__global__ void bn1_kernel(const float* __restrict__ src, const float* __restrict__ attn,
                           const float* __restrict__ gamma, const float* __restrict__ beta,
                           float* __restrict__ line_in) {
  const int d = blockIdx.x, line = blockIdx.y;
  float s1 = 0.f, s2 = 0.f;
  for (int i = threadIdx.x; i < B_ * L_; i += blockDim.x) {
    float v = (line == 0) ? src[i * D_ + d]
            : (line == 1) ? src[i * D_ + d] + attn[i * D_ + d]
                          : attn[i * D_ + d];
    s1 += v; s2 += v * v;
  }
#pragma unroll
  for (int off = 32; off > 0; off >>= 1) { s1 += __shfl_xor(s1, off, 64); s2 += __shfl_xor(s2, off, 64); }
  __shared__ float a1[4], a2[4];
  __shared__ float mean_s, rstd_s;
  int w = threadIdx.x >> 6;
  if ((threadIdx.x & 63) == 0) { a1[w] = s1; a2[w] = s2; }
  __syncthreads();
  if (threadIdx.x == 0) {
    float t1 = a1[0] + a1[1] + a1[2] + a1[3];
    float t2 = a2[0] + a2[1] + a2[2] + a2[3];
    float mean = t1 / (float)(B_ * L_);
    float var = t2 / (float)(B_ * L_) - mean * mean;
    mean_s = mean; rstd_s = rsqrtf(var + EPS_);
  }
  __syncthreads();
  const float mean = mean_s;
  const float gs = gamma[line * D_ + d] * rstd_s, be = beta[line * D_ + d];
  for (int i = threadIdx.x; i < B_ * L_; i += blockDim.x) {
    float v = (line == 0) ? src[i * D_ + d]
            : (line == 1) ? src[i * D_ + d] + attn[i * D_ + d]
                          : attn[i * D_ + d];
    line_in[line * B_ * L_ * D_ + i * D_ + d] = (v - mean) * gs + be;
  }
}

// ---------------- K5: fused two-layer LSTM recurrence ----------------
// R11: 24 WGs x 512 threads (8 waves, 1 CU each, __launch_bounds__(512,2)).
// layer = blk/12, line = (blk%12)/4, slice s = blk%4 (64 hidden units/WG).
// Wave w owns all 4 gates of units [s*64+w*8, +8) (2 N-tiles, K-full weights
// in VGPRs — same per-wave footprint as the 8-WG version).
// Handoff changes vs R9: (a) OWN h slice goes straight to LDS (no self
// round-trip through L3); (b) polls cover only the 3 REMOTE slices (3KB);
// (c) fan-in is 4 producers, reducing max-of-N jitter per step.
// Still flag-free: data is its own ready-flag vs the 0xAA poison.
template <int IN_K>
__device__ __forceinline__ void rec_body(
    const float* __restrict__ in_f32,           // layer0: line_in [3][B*L][64]
    const unsigned short* __restrict__ in_b16,  // layer1: hseq0 [3][L][B][H] fp16
    const float* __restrict__ Wih, const float* __restrict__ Whh,
    const float* __restrict__ bih, const float* __restrict__ bhh,
    unsigned short* __restrict__ hseq,          // out [3][L][B][H] fp16
    int line, int s,
    unsigned short (*hbuf)[B_][264], unsigned short (*xbuf)[B_][264]) {
  constexpr int NKT_IN = IN_K / 32;
  const int tid = threadIdx.x, w = tid >> 6, lane = tid & 63;
  const int q = lane >> 4, col = lane & 15;
  const int u = s * 64 + w * 8 + (col & 7);  // this lane's hidden unit

  // Register-resident fp16 weight fragments, gate-reordered rows:
  // n(T,col) = (T*2 + (col>>3))*H + u -> tile0 = i|f rows, tile1 = g|o rows.
  half8 whhF[2][8];
  half8 wihF[2][NKT_IN];
#pragma unroll
  for (int T = 0; T < 2; ++T) {
    const int n = (T * 2 + (col >> 3)) * H_ + u;
    const float* wr = &Whh[(size_t)(line * GH + n) * H_];
#pragma unroll
    for (int kt = 0; kt < 8; ++kt) {
      const float* pk = wr + kt * 32 + q * 8;
      half8 t;
#pragma unroll
      for (int j = 0; j < 8; ++j) t[j] = (_Float16)pk[j];
      whhF[T][kt] = t;
    }
    const float* wr2 = &Wih[(size_t)(line * GH + n) * IN_K];
#pragma unroll
    for (int kt = 0; kt < NKT_IN; ++kt) {
      const float* pk = wr2 + kt * 32 + q * 8;
      half8 t;
#pragma unroll
      for (int j = 0; j < 8; ++j) t[j] = (_Float16)pk[j];
      wihF[T][kt] = t;
    }
  }
  const float bI = bih[line * GH + 0 * H_ + u] + bhh[line * GH + 0 * H_ + u];
  const float bF = bih[line * GH + 1 * H_ + u] + bhh[line * GH + 1 * H_ + u];
  const float bG = bih[line * GH + 2 * H_ + u] + bhh[line * GH + 2 * H_ + u];
  const float bO = bih[line * GH + 3 * H_ + u] + bhh[line * GH + 3 * H_ + u];

  // Remote-h poll geometry (tid<192): remote slice rs 0..2 -> actual sa,
  // off: batch pb (0..7), 16B chunk pch (0..7) within the 128B slice-row.
  const int rs = tid / 64;
  const int sa = rs + (rs >= s ? 1 : 0);
  const int roff = tid % 64;
  const int rpb = roff >> 3, rpch = roff & 7;
  // x poll geometry (tid<256, layer1): batch xpb, chunk xpch of 512B row.
  const int xpb = tid >> 5, xpch = tid & 31;

  float cst[4] = {0.f, 0.f, 0.f, 0.f};

  for (int t = 0; t < L_; ++t) {
    const int buf = t & 1;

    // ---- stage step-t inputs: x_t and REMOTE h_{t-1} slices ----
    if constexpr (IN_K == 64) {
      if (tid < 64) {  // layer0 x: plain loads + fp16 cvt
        int b = tid >> 3, ch = tid & 7;
        const float* xp = &in_f32[((size_t)(line * B_ * L_) + b * L_ + t) * D_ + ch * 8];
        float4 f0 = *(const float4*)xp;
        float4 f1 = *(const float4*)(xp + 4);
        half8 a;
        a[0] = (_Float16)f0.x; a[1] = (_Float16)f0.y; a[2] = (_Float16)f0.z; a[3] = (_Float16)f0.w;
        a[4] = (_Float16)f1.x; a[5] = (_Float16)f1.y; a[6] = (_Float16)f1.z; a[7] = (_Float16)f1.w;
        *(half8*)&xbuf[buf][b][ch * 8] = a;
      }
      if (t > 0 && tid < 192) {
        const unsigned short* hp =
            hseq + ((size_t)(line * L_ + t - 1) * B_ + rpb) * H_ + sa * 64 + rpch * 8;
        u32x4 vh;
        do { poll1(hp, vh); } while (!ok4(vh));
        *(u32x4*)&hbuf[buf][rpb][sa * 64 + rpch * 8] = vh;
      }
    } else {
      const unsigned short* xp =
          in_b16 + ((size_t)(line * L_ + t) * B_ + xpb) * H_ + xpch * 8;
      if (t > 0 && tid < 192) {
        const unsigned short* hp =
            hseq + ((size_t)(line * L_ + t - 1) * B_ + rpb) * H_ + sa * 64 + rpch * 8;
        u32x4 vh, vx;
        do { poll2(hp, xp, vh, vx); } while (!(ok4(vh) && ok4(vx)));
        *(u32x4*)&hbuf[buf][rpb][sa * 64 + rpch * 8] = vh;
        *(u32x4*)&xbuf[buf][xpb][xpch * 8] = vx;
      } else if (tid < 256) {
        u32x4 vx;
        do { poll1(xp, vx); } while (!ok4(vx));
        *(u32x4*)&xbuf[buf][xpb][xpch * 8] = vx;
      }
    }
    __syncthreads();  // LDS[buf] ready (x + remote h + own h from t-1 update)

    // ---- gates: acc0 = (i|f) rows, acc1 = (g|o) rows ----
    f32x4 acc0 = {0.f, 0.f, 0.f, 0.f}, acc1 = {0.f, 0.f, 0.f, 0.f};
#pragma unroll
    for (int kt = 0; kt < NKT_IN; ++kt) {
      half8 a = *(const half8*)&xbuf[buf][col & 7][kt * 32 + q * 8];
      acc0 = __builtin_amdgcn_mfma_f32_16x16x32_f16(a, wihF[0][kt], acc0, 0, 0, 0);
      acc1 = __builtin_amdgcn_mfma_f32_16x16x32_f16(a, wihF[1][kt], acc1, 0, 0, 0);
    }
    if (t > 0) {
#pragma unroll
      for (int kt = 0; kt < 8; ++kt) {
        half8 a = *(const half8*)&hbuf[buf][col & 7][kt * 32 + q * 8];
        acc0 = __builtin_amdgcn_mfma_f32_16x16x32_f16(a, whhF[0][kt], acc0, 0, 0, 0);
        acc1 = __builtin_amdgcn_mfma_f32_16x16x32_f16(a, whhF[1][kt], acc1, 0, 0, 0);
      }
    }

    // ---- in-wave gate exchange + cell update ----
    // lane (q<2, col<8): i=acc0, g=acc1; partner (col+8): f=acc0, o=acc1.
    float fx[4], ox[4];
#pragma unroll
    for (int r = 0; r < 4; ++r) {
      fx[r] = __shfl_xor(acc0[r], 8, 64);
      ox[r] = __shfl_xor(acc1[r], 8, 64);
    }
    unsigned int hv[4] = {0u, 0u, 0u, 0u};
    if (q < 2 && col < 8) {
#pragma unroll
      for (int r = 0; r < 4; ++r) {
        float gi = fast_sig(acc0[r] + bI);
        float gf = fast_sig(fx[r] + bF);
        float gg = fast_tanh(acc1[r] + bG);
        float go = fast_sig(ox[r] + bO);
        cst[r] = gf * cst[r] + gi * gg;
        float h = go * fast_tanh(cst[r]);
        hv[r] = (unsigned int)f2h(h);
        // own slice -> LDS for OUR next step (no L3 round trip)
        hbuf[buf ^ 1][q * 4 + r][u] = (unsigned short)hv[r];
      }
    }
    unsigned int ov[4];
#pragma unroll
    for (int r = 0; r < 4; ++r) ov[r] = __shfl_xor(hv[r], 1, 64);
    if (q < 2 && col < 8 && !(col & 1)) {
#pragma unroll
      for (int r = 0; r < 4; ++r) {
        unsigned int packed = hv[r] | (ov[r] << 16);
        if (packed == POISON_) packed ^= 1u;  // sentinel collision: flip LSB
        __hip_atomic_store(
            (unsigned int*)&hseq[((size_t)(line * L_ + t) * B_ + (q * 4 + r)) * H_ + u],
            packed, __ATOMIC_RELAXED, __HIP_MEMORY_SCOPE_AGENT);
      }
    }
  }
}

__global__ __launch_bounds__(512, 2) void rec_fused_kernel(
    const float* __restrict__ line_in,
    const float* __restrict__ Wih0, const float* __restrict__ Whh0,
    const float* __restrict__ bih0, const float* __restrict__ bhh0,
    const float* __restrict__ Wih1, const float* __restrict__ Whh1,
    const float* __restrict__ bih1, const float* __restrict__ bhh1,
    unsigned short* __restrict__ hseq0, unsigned short* __restrict__ hseq1) {
  __shared__ __align__(16) unsigned short hbuf[2][B_][264];
  __shared__ __align__(16) unsigned short xbuf[2][B_][264];
  const int blk = blockIdx.x;
  const int layer = blk / 12, rem = blk % 12;
  const int line = rem >> 2, s = rem & 3;
  if (layer == 0)
    rec_body<64>(line_in, nullptr, Wih0, Whh0, bih0, bhh0, hseq0,
                 line, s, hbuf, xbuf);
  else
    rec_body<256>(nullptr, hseq0, Wih1, Whh1, bih1, bhh1, hseq1,
                  line, s, hbuf, xbuf);
}

// ---------------- K6a: bn2 statistics over weighted cat ----------------
__global__ void bn2stats_kernel(const unsigned short* __restrict__ hseq1,
                                const float* __restrict__ cat_w, float* __restrict__ stats) {
  const int h = blockIdx.x;
  float s1 = 0.f, s2 = 0.f;
  for (int i = threadIdx.x; i < B_ * L_; i += blockDim.x) {
    int l = i >> 3, b = i & 7;
    float w0 = cat_w[(0 * L_ + l) * H_ + h], w1 = cat_w[(1 * L_ + l) * H_ + h],
          w2 = cat_w[(2 * L_ + l) * H_ + h];
    float v0 = h2f(hseq1[((0 * L_ + l) * B_ + b) * H_ + h]);
    float v1 = h2f(hseq1[((1 * L_ + l) * B_ + b) * H_ + h]);
    float v2 = h2f(hseq1[((2 * L_ + l) * B_ + b) * H_ + h]);
    float v = (v0 * w0 + v1 * w1 + v2 * w2) / (w0 + w1 + w2);
    s1 += v; s2 += v * v;
  }
#pragma unroll
  for (int off = 32; off > 0; off >>= 1) { s1 += __shfl_xor(s1, off, 64); s2 += __shfl_xor(s2, off, 64); }
  __shared__ float a1[4], a2[4];
  int w = threadIdx.x >> 6;
  if ((threadIdx.x & 63) == 0) { a1[w] = s1; a2[w] = s2; }
  __syncthreads();
  if (threadIdx.x == 0) {
    float t1 = a1[0] + a1[1] + a1[2] + a1[3];
    float t2 = a2[0] + a2[1] + a2[2] + a2[3];
    float mean = t1 / (float)(B_ * L_);
    float var = t2 / (float)(B_ * L_) - mean * mean;
    stats[2 * h] = mean;
    stats[2 * h + 1] = rsqrtf(var + EPS_);
  }
}

// ---------------- K6b: normalize last timestep + FC ----------------
__global__ void final_kernel(const unsigned short* __restrict__ hseq1,
                             const float* __restrict__ cat_w, const float* __restrict__ stats,
                             const float* __restrict__ gamma, const float* __restrict__ beta,
                             const float* __restrict__ fcW, const float* __restrict__ fcb,
                             float* __restrict__ out) {
  const int h = threadIdx.x;  // 256
  __shared__ float vmat[B_][H_];
  const float mean = stats[2 * h], rstd = stats[2 * h + 1];
  const float g = gamma[h], be = beta[h];
  const int l = L_ - 1;
  float w0 = cat_w[(0 * L_ + l) * H_ + h], w1 = cat_w[(1 * L_ + l) * H_ + h],
        w2 = cat_w[(2 * L_ + l) * H_ + h];
  const float wsum = w0 + w1 + w2;
  for (int b = 0; b < B_; ++b) {
    float v0 = h2f(hseq1[((0 * L_ + l) * B_ + b) * H_ + h]);
    float v1 = h2f(hseq1[((1 * L_ + l) * B_ + b) * H_ + h]);
    float v2 = h2f(hseq1[((2 * L_ + l) * B_ + b) * H_ + h]);
    float v = (v0 * w0 + v1 * w1 + v2 * w2) / wsum;
    vmat[b][h] = (v - mean) * rstd * g + be;
  }
  __syncthreads();
  if (h < 64) {
    int b = h >> 3, c = h & 7;
    float acc = fcb[c];
    for (int k = 0; k < H_; ++k) acc += vmat[b][k] * fcW[c * H_ + k];
    out[b * 8 + c] = acc;
  }
}

extern "C" void kernel_launch(void* const* d_in, const int* in_sizes, int n_in,
                              void* d_out, int out_size, void* d_ws, size_t ws_size,
                              hipStream_t stream) {
  (void)in_sizes; (void)n_in; (void)out_size; (void)ws_size;
  const float* src       = (const float*)d_in[0];
  const float* attn_w    = (const float*)d_in[1];
  const float* cat_w     = (const float*)d_in[2];
  const float* bn1_gamma = (const float*)d_in[3];
  const float* bn1_beta  = (const float*)d_in[4];
  const float* bn2_gamma = (const float*)d_in[5];
  const float* bn2_beta  = (const float*)d_in[6];
  const float* Wih0      = (const float*)d_in[7];
  const float* Whh0      = (const float*)d_in[8];
  const float* bih0      = (const float*)d_in[9];
  const float* bhh0      = (const float*)d_in[10];
  const float* Wih1      = (const float*)d_in[11];
  const float* Whh1      = (const float*)d_in[12];
  const float* bih1      = (const float*)d_in[13];
  const float* bhh1      = (const float*)d_in[14];
  const float* fcW       = (const float*)d_in[15];
  const float* fcb       = (const float*)d_in[16];
  float* out = (float*)d_out;

  char* p = (char*)d_ws;
  float* Sp = (float*)p;                      p += (size_t)B_ * L_ * L_ * 4;
  float* Sa = (float*)p;                      p += (size_t)B_ * L_ * L_ * 4;
  float* outk = (float*)p;                    p += (size_t)3 * B_ * L_ * D_ * 4;
  float* attn = (float*)p;                    p += (size_t)B_ * L_ * D_ * 4;
  float* line_in = (float*)p;                 p += (size_t)3 * B_ * L_ * D_ * 4;
  float* stats = (float*)p;                   p += (size_t)512 * 4;
  unsigned short* hseq0 = (unsigned short*)p; p += (size_t)3 * L_ * B_ * H_ * 2;
  unsigned short* hseq1 = (unsigned short*)p; p += (size_t)3 * L_ * B_ * H_ * 2;

  scores_kernel<<<dim3(L_, B_), dim3(256), 0, stream>>>(src, Sp, Sa);
  softmax_av_kernel<<<dim3(L_, B_, 3), dim3(64), 0, stream>>>(src, Sp, Sa, outk);
  combine_kernel<<<dim3((B_ * L_ * D_) / 256), dim3(256), 0, stream>>>(outk, attn_w, attn);
  bn1_kernel<<<dim3(D_, 3), dim3(256), 0, stream>>>(src, attn, bn1_gamma, bn1_beta, line_in);
  rec_fused_kernel<<<dim3(24), dim3(512), 0, stream>>>(
      line_in, Wih0, Whh0, bih0, bhh0, Wih1, Whh1, bih1, bhh1, hseq0, hseq1);
  bn2stats_kernel<<<dim3(H_), dim3(256), 0, stream>>>(hseq1, cat_w, stats);
  final_kernel<<<dim3(1), dim3(256), 0, stream>>>(hseq1, cat_w, stats, bn2_gamma, bn2_beta,
                                                  fcW, fcb, out);
}

// Round 12
// 1306.828 us; speedup vs baseline: 1.2731x; 1.2731x over previous
//
#include <hip/hip_runtime.h>

#define B_ 8
#define L_ 512
#define D_ 64
#define H_ 256
#define GH 1024   // 4*H
#define EPS_ 1e-5f
#define POISON_ 0xAAAAAAAAu  // harness poisons d_ws to 0xAA bytes every launch

typedef float f32x4 __attribute__((ext_vector_type(4)));
typedef _Float16 half8 __attribute__((ext_vector_type(8)));

__device__ __forceinline__ unsigned short f2h(float f) {
  _Float16 h = (_Float16)f;
  return __builtin_bit_cast(unsigned short, h);
}
__device__ __forceinline__ float h2f(unsigned short s) {
  _Float16 h = __builtin_bit_cast(_Float16, s);
  return (float)h;
}
__device__ __forceinline__ float fast_tanh(float x) {
  return 1.0f - 2.0f / (1.0f + __expf(2.0f * x));
}
__device__ __forceinline__ float fast_sig(float x) {
  return 1.0f / (1.0f + __expf(-x));
}
__device__ __forceinline__ unsigned int load_agent(const unsigned int* p) {
  return __hip_atomic_load(p, __ATOMIC_RELAXED, __HIP_MEMORY_SCOPE_AGENT);
}

// ---------------- K1: fused attention (scores + 3x softmax + P@x) ----------------
// Block (l,b), 256 threads. Scores into LDS; waves 0..2 each run one
// attention variant's causal softmax + P@x. Saves the S-matrix HBM round
// trip and one kernel launch vs the split version.
__global__ void attn_kernel(const float* __restrict__ src, float* __restrict__ outk) {
  const int l = blockIdx.x, b = blockIdx.y;
  const int tid = threadIdx.x, w = tid >> 6, lane = tid & 63;
  __shared__ float xl[D_];
  __shared__ float sp[L_], sa[L_];
  __shared__ float pk[3][L_];
  if (tid < D_) xl[tid] = src[(b * L_ + l) * D_ + tid];
  __syncthreads();
  for (int m = tid; m <= l; m += 256) {
    const float4* xr = (const float4*)&src[(b * L_ + m) * D_];
    float dp = 0.f, da = 0.f;
#pragma unroll
    for (int d4 = 0; d4 < D_ / 4; ++d4) {
      float4 v = xr[d4];
      dp += xl[d4*4+0]*v.x + xl[d4*4+1]*v.y + xl[d4*4+2]*v.z + xl[d4*4+3]*v.w;
      da += fast_tanh(xl[d4*4+0]+v.x) + fast_tanh(xl[d4*4+1]+v.y)
          + fast_tanh(xl[d4*4+2]+v.z) + fast_tanh(xl[d4*4+3]+v.w);
    }
    sp[m] = dp;
    sa[m] = da;
  }
  __syncthreads();
  if (w < 3) {  // wave w handles attention variant w: 0=plain,1=additive,2=sdpa
    const float scale = (w == 2) ? 0.125f : 1.0f;
    float mx = -1e30f;
    for (int m = lane; m <= l; m += 64) {
      float v = ((w == 1) ? sa[m] : sp[m]) * scale;
      pk[w][m] = v;
      mx = fmaxf(mx, v);
    }
#pragma unroll
    for (int off = 32; off > 0; off >>= 1) mx = fmaxf(mx, __shfl_xor(mx, off, 64));
    float sum = 0.f;
    for (int m = lane; m <= l; m += 64) {
      float e = __expf(pk[w][m] - mx);
      pk[w][m] = e;
      sum += e;
    }
#pragma unroll
    for (int off = 32; off > 0; off >>= 1) sum += __shfl_xor(sum, off, 64);
    const float inv = 1.0f / sum;
    float acc = 0.f;
    for (int m = 0; m <= l; ++m) acc += pk[w][m] * src[(b * L_ + m) * D_ + lane];
    outk[((w * B_ + b) * L_ + l) * D_ + lane] = acc * inv;
  }
}

// ---------------- K3a: weighted combine ----------------
__global__ void combine_kernel(const float* __restrict__ outk, const float* __restrict__ attn_w,
                               float* __restrict__ attn) {
  int i = blockIdx.x * blockDim.x + threadIdx.x;
  if (i >= B_ * L_ * D_) return;
  int ld = i & (L_ * D_ - 1);
  float w0 = attn_w[ld], w1 = attn_w[L_ * D_ + ld], w2 = attn_w[2 * L_ * D_ + ld];
  float o0 = outk[i], o1 = outk[B_ * L_ * D_ + i], o2 = outk[2 * B_ * L_ * D_ + i];
  attn[i] = (o0 * w0 + o1 * w1 + o2 * w2) / (w0 + w1 + w2);
}

// ---------------- K3b: BatchNorm over (B,L) per feature, 3 lines ----------------
__global__ void bn1_kernel(const float* __restrict__ src, const float* __restrict__ attn,
                           const float* __restrict__ gamma, const float* __restrict__ beta,
                           float* __restrict__ line_in) {
  const int d = blockIdx.x, line = blockIdx.y;
  float s1 = 0.f, s2 = 0.f;
  for (int i = threadIdx.x; i < B_ * L_; i += blockDim.x) {
    float v = (line == 0) ? src[i * D_ + d]
            : (line == 1) ? src[i * D_ + d] + attn[i * D_ + d]
                          : attn[i * D_ + d];
    s1 += v; s2 += v * v;
  }
#pragma unroll
  for (int off = 32; off > 0; off >>= 1) { s1 += __shfl_xor(s1, off, 64); s2 += __shfl_xor(s2, off, 64); }
  __shared__ float a1[4], a2[4];
  __shared__ float mean_s, rstd_s;
  int w = threadIdx.x >> 6;
  if ((threadIdx.x & 63) == 0) { a1[w] = s1; a2[w] = s2; }
  __syncthreads();
  if (threadIdx.x == 0) {
    float t1 = a1[0] + a1[1] + a1[2] + a1[3];
    float t2 = a2[0] + a2[1] + a2[2] + a2[3];
    float mean = t1 / (float)(B_ * L_);
    float var = t2 / (float)(B_ * L_) - mean * mean;
    mean_s = mean; rstd_s = rsqrtf(var + EPS_);
  }
  __syncthreads();
  const float mean = mean_s;
  const float gs = gamma[line * D_ + d] * rstd_s, be = beta[line * D_ + d];
  for (int i = threadIdx.x; i < B_ * L_; i += blockDim.x) {
    float v = (line == 0) ? src[i * D_ + d]
            : (line == 1) ? src[i * D_ + d] + attn[i * D_ + d]
                          : attn[i * D_ + d];
    line_in[line * B_ * L_ * D_ + i * D_ + d] = (v - mean) * gs + be;
  }
}

// ---------------- K5: fused two-layer LSTM recurrence (R7 + s_sleep backoff) ----------------
// 48 WGs: layer = blk/24, line = (blk%24)/8, slice s = blk%8 (32 hidden units).
// Sync: NO flags, NO drains, agent-scope relaxed atomics only. Round-based
// batched polls (all pending dwords reloaded per round, one waitcnt).
// R12: EXPONENTIAL s_sleep BACKOFF on poll miss — first check free, then
// s_sleep 1, then s_sleep 4 — to stop waiting threads from flooding the L3
// home slices of the polled lines (theory: poll-traffic queueing delay is
// the ~2.1us/step floor, not the intrinsic store->visible latency).
template <int IN_K>
__device__ __forceinline__ void rec_body(
    const float* __restrict__ in_f32,           // layer0: line_in [3][B*L][64]
    const unsigned short* __restrict__ in_b16,  // layer1: hseq0 [3][L][B][H] fp16
    const float* __restrict__ Wih, const float* __restrict__ Whh,
    const float* __restrict__ bih, const float* __restrict__ bhh,
    unsigned short* __restrict__ hseq,          // out [3][L][B][H] fp16
    int line, int s,
    unsigned short* hprev, unsigned short* inbuf,
    float (*gbuf)[32][8], float (*biasS)[32]) {
  constexpr int INROW = IN_K + 8;
  constexpr int NKT_IN = IN_K / 32;
  const int tid = threadIdx.x, w = tid >> 6, lane = tid & 63;
  const int q = lane >> 4, col = lane & 15;

  // Register-resident fp16 weight fragments (wave w <-> gate w, tiles T=0,1).
  half8 whhF[2][8];
  half8 wihF[2][NKT_IN];
#pragma unroll
  for (int T = 0; T < 2; ++T) {
    const int n = w * H_ + s * 32 + T * 16 + col;
    const float* wr = &Whh[(line * GH + n) * H_];
#pragma unroll
    for (int kt = 0; kt < 8; ++kt) {
      const float* pk = wr + kt * 32 + q * 8;
      half8 t;
#pragma unroll
      for (int j = 0; j < 8; ++j) t[j] = (_Float16)pk[j];
      whhF[T][kt] = t;
    }
    const float* wr2 = &Wih[(line * GH + n) * IN_K];
#pragma unroll
    for (int kt = 0; kt < NKT_IN; ++kt) {
      const float* pk = wr2 + kt * 32 + q * 8;
      half8 t;
#pragma unroll
      for (int j = 0; j < 8; ++j) t[j] = (_Float16)pk[j];
      wihF[T][kt] = t;
    }
  }
  if (tid < 128) {
    int g = tid >> 5, j = tid & 31;
    int n = g * H_ + s * 32 + j;
    biasS[g][j] = bih[line * GH + n] + bhh[line * GH + n];
  }
  for (int i = tid; i < 16 * 264; i += 256) hprev[i] = 0;
  for (int i = tid; i < 16 * INROW; i += 256) inbuf[i] = 0;

  // Per-thread gather geometry (constant across steps).
  int gdst[4];
  bool gremote[4];
  int goff[4];  // short offset within hseq[line][t] row
#pragma unroll
  for (int rr = 0; rr < 4; ++rr) {
    int u = tid + rr * 256;
    int r = u >> 7, v = u & 127, b = v >> 4, pz = v & 15;
    int cidx = r * 32 + pz * 2;
    gremote[rr] = (r != s);
    gdst[rr] = b * 264 + cidx;
    goff[rr] = b * H_ + cidx;
  }

  // Initial stage of x_0 (round-based for layer1, with backoff).
  if constexpr (IN_K == 64) {
#pragma unroll
    for (int r = 0; r < 2; ++r) {
      int idx = tid + r * 256;
      int b = idx >> 6, d = idx & 63;
      inbuf[b * INROW + d] = f2h(in_f32[(line * B_ * L_ + b * L_ + 0) * D_ + d]);
    }
  } else {
    const unsigned int* sa[4];
    unsigned int sv[4];
#pragma unroll
    for (int r = 0; r < 4; ++r) {
      int u = tid + r * 256;
      int b = u >> 7, pr = u & 127;
      sa[r] = (const unsigned int*)&in_b16[((line * L_ + 0) * B_ + b) * H_ + pr * 2];
    }
    int miss = 0;
    for (;;) {
#pragma unroll
      for (int r = 0; r < 4; ++r) sv[r] = load_agent(sa[r]);
      bool ready = true;
#pragma unroll
      for (int r = 0; r < 4; ++r) ready = ready && (sv[r] != POISON_);
      if (ready) break;
      if (miss == 0) { asm volatile("s_sleep 1"); miss = 1; }
      else asm volatile("s_sleep 4");
    }
#pragma unroll
    for (int r = 0; r < 4; ++r) {
      int u = tid + r * 256;
      int b = u >> 7, pr = u & 127;
      *(unsigned int*)&inbuf[b * INROW + pr * 2] = sv[r];
    }
  }

  float c0 = 0.f, c1 = 0.f;
  const int ub = tid & 7, jp = (tid >> 3) * 2;  // valid for tid<128
  __syncthreads();

  for (int t = 0; t < L_; ++t) {
    // (1) gates = x_t·Wih^T + h_{t-1}·Whh^T  (fp16 MFMA, fp32 acc)
    f32x4 acc0 = {0.f, 0.f, 0.f, 0.f}, acc1 = {0.f, 0.f, 0.f, 0.f};
#pragma unroll
    for (int kt = 0; kt < NKT_IN; ++kt) {
      half8 a = *(const half8*)&inbuf[col * INROW + kt * 32 + q * 8];
      acc0 = __builtin_amdgcn_mfma_f32_16x16x32_f16(a, wihF[0][kt], acc0, 0, 0, 0);
      acc1 = __builtin_amdgcn_mfma_f32_16x16x32_f16(a, wihF[1][kt], acc1, 0, 0, 0);
    }
#pragma unroll
    for (int kt = 0; kt < 8; ++kt) {
      half8 a = *(const half8*)&hprev[col * 264 + kt * 32 + q * 8];
      acc0 = __builtin_amdgcn_mfma_f32_16x16x32_f16(a, whhF[0][kt], acc0, 0, 0, 0);
      acc1 = __builtin_amdgcn_mfma_f32_16x16x32_f16(a, whhF[1][kt], acc1, 0, 0, 0);
    }
    if (q < 2) {  // D layout: n = lane&15, m(batch) = q*4+r; only m<8 real
#pragma unroll
      for (int r = 0; r < 4; ++r) {
        gbuf[w][col][q * 4 + r] = acc0[r];
        gbuf[w][16 + col][q * 4 + r] = acc1[r];
      }
    }
    __syncthreads();  // B1

    // (2) cell update: tid<128, batch ub, hidden pair (jp, jp+1).
    //     Global h store is fire-and-forget (data is its own ready-flag).
    if (tid < 128) {
      float gi0 = gbuf[0][jp][ub] + biasS[0][jp];
      float gf0 = gbuf[1][jp][ub] + biasS[1][jp];
      float gg0 = gbuf[2][jp][ub] + biasS[2][jp];
      float go0 = gbuf[3][jp][ub] + biasS[3][jp];
      float gi1 = gbuf[0][jp+1][ub] + biasS[0][jp+1];
      float gf1 = gbuf[1][jp+1][ub] + biasS[1][jp+1];
      float gg1 = gbuf[2][jp+1][ub] + biasS[2][jp+1];
      float go1 = gbuf[3][jp+1][ub] + biasS[3][jp+1];
      c0 = fast_sig(gf0) * c0 + fast_sig(gi0) * fast_tanh(gg0);
      c1 = fast_sig(gf1) * c1 + fast_sig(gi1) * fast_tanh(gg1);
      float h0 = fast_sig(go0) * fast_tanh(c0);
      float h1 = fast_sig(go1) * fast_tanh(c1);
      unsigned int packed = (unsigned int)f2h(h0) | ((unsigned int)f2h(h1) << 16);
      if (packed == POISON_) packed ^= 1u;  // sentinel collision: flip LSB (2^-11)
      __hip_atomic_store(
          (unsigned int*)&hseq[((line * L_ + t) * B_ + ub) * H_ + s * 32 + jp],
          packed, __ATOMIC_RELAXED, __HIP_MEMORY_SCOPE_AGENT);
      *(unsigned int*)&hprev[ub * 264 + s * 32 + jp] = packed;
    }

    if (t == L_ - 1) break;  // last stores retire on their own

    // (3) ROUND-BASED poll with backoff: remote h (4 dwords) + layer1
    //     next-x (4 dwords) reloaded together each round; one waitcnt.
    const unsigned short* hrow = &hseq[(size_t)(line * L_ + t) * B_ * H_];
    const unsigned int* ga[4];
    unsigned int gv[4];
#pragma unroll
    for (int rr = 0; rr < 4; ++rr) ga[rr] = (const unsigned int*)(hrow + goff[rr]);

    if constexpr (IN_K == 64) {
      // layer0: stage x_{t+1} with plain loads (overlaps the poll rounds)
#pragma unroll
      for (int r = 0; r < 2; ++r) {
        int idx = tid + r * 256;
        int b = idx >> 6, d = idx & 63;
        inbuf[b * INROW + d] = f2h(in_f32[(line * B_ * L_ + b * L_ + t + 1) * D_ + d]);
      }
      int miss = 0;
      for (;;) {
#pragma unroll
        for (int rr = 0; rr < 4; ++rr) gv[rr] = load_agent(ga[rr]);
        bool ready = true;
#pragma unroll
        for (int rr = 0; rr < 4; ++rr)
          ready = ready && (!gremote[rr] || gv[rr] != POISON_);
        if (ready) break;
        if (miss == 0) { asm volatile("s_sleep 1"); miss = 1; }
        else asm volatile("s_sleep 4");
      }
    } else {
      const unsigned int* sa[4];
      unsigned int sv[4];
#pragma unroll
      for (int r = 0; r < 4; ++r) {
        int u = tid + r * 256;
        int b = u >> 7, pr = u & 127;
        sa[r] = (const unsigned int*)&in_b16[((line * L_ + t + 1) * B_ + b) * H_ + pr * 2];
      }
      int miss = 0;
      for (;;) {
#pragma unroll
        for (int rr = 0; rr < 4; ++rr) gv[rr] = load_agent(ga[rr]);
#pragma unroll
        for (int r = 0; r < 4; ++r) sv[r] = load_agent(sa[r]);
        bool ready = true;
#pragma unroll
        for (int rr = 0; rr < 4; ++rr)
          ready = ready && (!gremote[rr] || gv[rr] != POISON_);
#pragma unroll
        for (int r = 0; r < 4; ++r) ready = ready && (sv[r] != POISON_);
        if (ready) break;
        if (miss == 0) { asm volatile("s_sleep 1"); miss = 1; }
        else asm volatile("s_sleep 4");
      }
#pragma unroll
      for (int r = 0; r < 4; ++r) {
        int u = tid + r * 256;
        int b = u >> 7, pr = u & 127;
        *(unsigned int*)&inbuf[b * INROW + pr * 2] = sv[r];
      }
    }
#pragma unroll
    for (int rr = 0; rr < 4; ++rr)
      if (gremote[rr]) *(unsigned int*)&hprev[gdst[rr]] = gv[rr];
    __syncthreads();  // B2: hprev/inbuf ready for next MFMA
  }
}

__global__ __launch_bounds__(256, 1) void rec_fused_kernel(
    const float* __restrict__ line_in,
    const float* __restrict__ Wih0, const float* __restrict__ Whh0,
    const float* __restrict__ bih0, const float* __restrict__ bhh0,
    const float* __restrict__ Wih1, const float* __restrict__ Whh1,
    const float* __restrict__ bih1, const float* __restrict__ bhh1,
    unsigned short* __restrict__ hseq0, unsigned short* __restrict__ hseq1) {
  __shared__ unsigned short hprev[16 * 264];
  __shared__ unsigned short inbuf[16 * 264];
  __shared__ float gbuf[4][32][8];
  __shared__ float biasS[4][32];
  const int blk = blockIdx.x;
  const int layer = blk / 24, rem = blk % 24;
  const int line = rem >> 3, s = rem & 7;
  if (layer == 0)
    rec_body<64>(line_in, nullptr, Wih0, Whh0, bih0, bhh0, hseq0,
                 line, s, hprev, inbuf, gbuf, biasS);
  else
    rec_body<256>(nullptr, hseq0, Wih1, Whh1, bih1, bhh1, hseq1,
                  line, s, hprev, inbuf, gbuf, biasS);
}

// ---------------- K6a: bn2 statistics over weighted cat ----------------
__global__ void bn2stats_kernel(const unsigned short* __restrict__ hseq1,
                                const float* __restrict__ cat_w, float* __restrict__ stats) {
  const int h = blockIdx.x;
  float s1 = 0.f, s2 = 0.f;
  for (int i = threadIdx.x; i < B_ * L_; i += blockDim.x) {
    int l = i >> 3, b = i & 7;
    float w0 = cat_w[(0 * L_ + l) * H_ + h], w1 = cat_w[(1 * L_ + l) * H_ + h],
          w2 = cat_w[(2 * L_ + l) * H_ + h];
    float v0 = h2f(hseq1[((0 * L_ + l) * B_ + b) * H_ + h]);
    float v1 = h2f(hseq1[((1 * L_ + l) * B_ + b) * H_ + h]);
    float v2 = h2f(hseq1[((2 * L_ + l) * B_ + b) * H_ + h]);
    float v = (v0 * w0 + v1 * w1 + v2 * w2) / (w0 + w1 + w2);
    s1 += v; s2 += v * v;
  }
#pragma unroll
  for (int off = 32; off > 0; off >>= 1) { s1 += __shfl_xor(s1, off, 64); s2 += __shfl_xor(s2, off, 64); }
  __shared__ float a1[4], a2[4];
  int w = threadIdx.x >> 6;
  if ((threadIdx.x & 63) == 0) { a1[w] = s1; a2[w] = s2; }
  __syncthreads();
  if (threadIdx.x == 0) {
    float t1 = a1[0] + a1[1] + a1[2] + a1[3];
    float t2 = a2[0] + a2[1] + a2[2] + a2[3];
    float mean = t1 / (float)(B_ * L_);
    float var = t2 / (float)(B_ * L_) - mean * mean;
    stats[2 * h] = mean;
    stats[2 * h + 1] = rsqrtf(var + EPS_);
  }
}

// ---------------- K6b: normalize last timestep + FC ----------------
__global__ void final_kernel(const unsigned short* __restrict__ hseq1,
                             const float* __restrict__ cat_w, const float* __restrict__ stats,
                             const float* __restrict__ gamma, const float* __restrict__ beta,
                             const float* __restrict__ fcW, const float* __restrict__ fcb,
                             float* __restrict__ out) {
  const int h = threadIdx.x;  // 256
  __shared__ float vmat[B_][H_];
  const float mean = stats[2 * h], rstd = stats[2 * h + 1];
  const float g = gamma[h], be = beta[h];
  const int l = L_ - 1;
  float w0 = cat_w[(0 * L_ + l) * H_ + h], w1 = cat_w[(1 * L_ + l) * H_ + h],
        w2 = cat_w[(2 * L_ + l) * H_ + h];
  const float wsum = w0 + w1 + w2;
  for (int b = 0; b < B_; ++b) {
    float v0 = h2f(hseq1[((0 * L_ + l) * B_ + b) * H_ + h]);
    float v1 = h2f(hseq1[((1 * L_ + l) * B_ + b) * H_ + h]);
    float v2 = h2f(hseq1[((2 * L_ + l) * B_ + b) * H_ + h]);
    float v = (v0 * w0 + v1 * w1 + v2 * w2) / wsum;
    vmat[b][h] = (v - mean) * rstd * g + be;
  }
  __syncthreads();
  if (h < 64) {
    int b = h >> 3, c = h & 7;
    float acc = fcb[c];
    for (int k = 0; k < H_; ++k) acc += vmat[b][k] * fcW[c * H_ + k];
    out[b * 8 + c] = acc;
  }
}

extern "C" void kernel_launch(void* const* d_in, const int* in_sizes, int n_in,
                              void* d_out, int out_size, void* d_ws, size_t ws_size,
                              hipStream_t stream) {
  (void)in_sizes; (void)n_in; (void)out_size; (void)ws_size;
  const float* src       = (const float*)d_in[0];
  const float* attn_w    = (const float*)d_in[1];
  const float* cat_w     = (const float*)d_in[2];
  const float* bn1_gamma = (const float*)d_in[3];
  const float* bn1_beta  = (const float*)d_in[4];
  const float* bn2_gamma = (const float*)d_in[5];
  const float* bn2_beta  = (const float*)d_in[6];
  const float* Wih0      = (const float*)d_in[7];
  const float* Whh0      = (const float*)d_in[8];
  const float* bih0      = (const float*)d_in[9];
  const float* bhh0      = (const float*)d_in[10];
  const float* Wih1      = (const float*)d_in[11];
  const float* Whh1      = (const float*)d_in[12];
  const float* bih1      = (const float*)d_in[13];
  const float* bhh1      = (const float*)d_in[14];
  const float* fcW       = (const float*)d_in[15];
  const float* fcb       = (const float*)d_in[16];
  float* out = (float*)d_out;

  char* p = (char*)d_ws;
  float* outk = (float*)p;                    p += (size_t)3 * B_ * L_ * D_ * 4;
  float* attn = (float*)p;                    p += (size_t)B_ * L_ * D_ * 4;
  float* line_in = (float*)p;                 p += (size_t)3 * B_ * L_ * D_ * 4;
  float* stats = (float*)p;                   p += (size_t)512 * 4;
  unsigned short* hseq0 = (unsigned short*)p; p += (size_t)3 * L_ * B_ * H_ * 2;
  unsigned short* hseq1 = (unsigned short*)p; p += (size_t)3 * L_ * B_ * H_ * 2;

  attn_kernel<<<dim3(L_, B_), dim3(256), 0, stream>>>(src, outk);
  combine_kernel<<<dim3((B_ * L_ * D_) / 256), dim3(256), 0, stream>>>(outk, attn_w, attn);
  bn1_kernel<<<dim3(D_, 3), dim3(256), 0, stream>>>(src, attn, bn1_gamma, bn1_beta, line_in);
  rec_fused_kernel<<<dim3(48), dim3(256), 0, stream>>>(
      line_in, Wih0, Whh0, bih0, bhh0, Wih1, Whh1, bih1, bhh1, hseq0, hseq1);
  bn2stats_kernel<<<dim3(H_), dim3(256), 0, stream>>>(hseq1, cat_w, stats);
  final_kernel<<<dim3(1), dim3(256), 0, stream>>>(hseq1, cat_w, stats, bn2_gamma, bn2_beta,
                                                  fcW, fcb, out);
}